// Round 5
// baseline (246.933 us; speedup 1.0000x reference)
//
#include <hip/hip_runtime.h>

typedef __attribute__((ext_vector_type(8))) short bf16x8;
typedef __attribute__((ext_vector_type(4))) float f32x4;
typedef __attribute__((ext_vector_type(4))) int i32x4;
typedef __attribute__((ext_vector_type(4))) unsigned short u16x4;

#define KDIM 256
#define HWSZ 4096
#define NOUT 765
#define NOUTP 768
#define UPB 8          // units per block; unit = 16 px x all 765 outputs

// Anchors in PIXEL units: w_a = ANCHORS/16 (grid units) and every use multiplies
// by STRIDE=16, so pixel units are exact.
__constant__ float c_AW[9] = {10.f,16.f,33.f,30.f,62.f,59.f,116.f,156.f,373.f};
__constant__ float c_AH[9] = {13.f,30.f,23.f,61.f,45.f,119.f,90.f,198.f,326.f};

__device__ __forceinline__ unsigned short f2bf(float f) {
  unsigned u = __builtin_bit_cast(unsigned, f);
  u += 0x7fffu + ((u >> 16) & 1u);   // RNE
  return (unsigned short)(u >> 16);
}

__device__ __forceinline__ float sigf(float t) {
  return 1.0f / (1.0f + __expf(-t));
}

// LDS-hazard-only barrier: lgkmcnt(0) (my ds ops done) -> s_barrier -> sched fence
// (rule 18: keep later LDS ops from hoisting above the barrier). Unlike
// __syncthreads() this does NOT drain vmcnt, so prefetch global_loads and the
// output store stream stay in flight across it (T4 counted-vmcnt spirit).
__device__ __forceinline__ void bar_lds() {
  asm volatile("s_waitcnt lgkmcnt(0)" ::: "memory");
  __builtin_amdgcn_s_barrier();
  __builtin_amdgcn_sched_barrier(0);
}

// ---- kernel 1: conv_w (765x256 f32) -> padded bf16 (768x256), rows 765..767 = 0
__global__ void prep_w(const float* __restrict__ cw, unsigned short* __restrict__ wbf) {
  int e = (blockIdx.x * 256 + threadIdx.x) * 4;
  int o = e >> 8, col = e & 255;
  f32x4 v = {0.f, 0.f, 0.f, 0.f};
  if (o < NOUT) v = *reinterpret_cast<const f32x4*>(cw + o * KDIM + col);
  u16x4 u = { f2bf(v.x), f2bf(v.y), f2bf(v.z), f2bf(v.w) };
  *reinterpret_cast<u16x4*>(wbf + e) = u;
}

// ---- kernel 2: persistent. 512 blocks (2/CU, whole grid resident), each loops
// UPB=8 units; unit = (b, py, 16-px quarter-row) x all 765 outputs.
// Per unit: {issue next-X prefetch} -> GEMM (8kk x 6ot MFMA) -> decode+deposit
// all 9 anchors into stg -> bar -> dense copy-out (6 dwordx4/thr) + cvt/write
// next xT buffer -> bar.  2 LDS-only barriers per unit.
// NO min-waves launch bound (this toolchain's (512,N>=4) forces spill — r2/r3).
__global__ __launch_bounds__(512) void yolo_main(
    const float* __restrict__ xin,
    const unsigned short* __restrict__ wbf,
    const float* __restrict__ bias,
    float* __restrict__ out)
{
  __shared__ __align__(16) unsigned short xT[2][16 * 256];  // 2 x 8 KB, k-bits 3..5 XOR-swizzled by px&7
  __shared__ __align__(16) float stg[9 * 16 * 85];          // 48.96 KB decoded staging

  const int tid  = threadIdx.x;
  const int lane = tid & 63;
  const int wv   = tid >> 6;
  const int g    = lane >> 4;
  const int r16  = lane & 15;
  const int obase = wv * 96;

  const int u0 = blockIdx.x * UPB;
  const int b  = u0 >> 8;                       // same b for all 8 units (8 | 256)

  // staging thread mapping: thread covers (px = tid&15, c-chunk = tid>>4) x 8 c's
  const int spx = tid & 15;
  const int sck = tid >> 4;                     // 0..31
  const int sxe = spx * 256 + ((sck * 8) ^ ((spx & 7) << 3));   // xT element index
  const float* xsb = xin + (size_t)b * (KDIM * HWSZ);

  // ---- per-ot decode constants (compile-time-indexed arrays -> scalars) ----
  float aw6[6], ah6[6], bi6[6];
  int   sof[6], och[6];
  #pragma unroll
  for (int ot = 0; ot < 6; ++ot) {
    const int o  = obase + ot * 16 + r16;
    const int a  = o / 85;                      // 9 for padded o 765..767
    const int ch = o - a * 85;
    och[ot] = ch;
    const int ac = a < 9 ? a : 8;
    aw6[ot] = c_AW[ac]; ah6[ot] = c_AH[ac];
    bi6[ot] = bias[o < NOUT ? o : 0];
    sof[ot] = a < 9 ? a * 1360 + ch : -1;       // -1 = padded, skip
  }
  // ---- per-thread copy-out offsets (unit-independent part) ----
  unsigned cOff[6];
  #pragma unroll
  for (int m = 0; m < 6; ++m) {
    const int qq = tid + 512 * m;               // quad index in stg, < 3060 (guarded at use)
    const int a  = qq / 340;
    cOff[m] = (unsigned)a * (HWSZ * 85u) + (unsigned)(qq - a * 340) * 4u;
  }

  const unsigned short* wp0 = wbf + (unsigned)(obase + r16) * KDIM + 8 * g;

  // ---- prologue: stage unit u0 into xT[0] ----
  {
    const int py = (u0 >> 2) & 63, q = u0 & 3;
    const float* xs = xsb + py * 64 + q * 16 + spx;
    float v[8];
    #pragma unroll
    for (int j = 0; j < 8; ++j) v[j] = xs[(size_t)(sck * 8 + j) * HWSZ];
    union { i32x4 qv; unsigned short us[8]; } pk;
    #pragma unroll
    for (int j = 0; j < 8; ++j) pk.us[j] = f2bf(v[j]);
    *reinterpret_cast<i32x4*>(&xT[0][sxe]) = pk.qv;
  }
  bar_lds();

  float pf[8];
  #pragma unroll 1
  for (int i = 0; i < UPB; ++i) {
    const int u  = u0 + i;
    const int py = (u >> 2) & 63, q = u & 3;

    // ---- issue next unit's X loads early (hide HBM latency under GEMM+deposit) ----
    if (i + 1 < UPB) {
      const int un = u + 1;
      const int pyn = (un >> 2) & 63, qn = un & 3;
      const float* xs = xsb + pyn * 64 + qn * 16 + spx;
      #pragma unroll
      for (int j = 0; j < 8; ++j) pf[j] = xs[(size_t)(sck * 8 + j) * HWSZ];
    }

    // ---- GEMM: D[px][o], A = X (px=r16), B = W (o), k-permutation cancels ----
    f32x4 acc[6];
    #pragma unroll
    for (int ot = 0; ot < 6; ++ot) acc[ot] = f32x4{0.f, 0.f, 0.f, 0.f};
    const unsigned short* xb = &xT[i & 1][0];
    const int kxor = (r16 & 7) << 3;
    #pragma unroll
    for (int kk = 0; kk < 8; ++kk) {
      const int ke = (kk * 32 + 8 * g) ^ kxor;
      bf16x8 x0 = __builtin_bit_cast(bf16x8,
          *reinterpret_cast<const i32x4*>(&xb[r16 * 256 + ke]));
      #pragma unroll
      for (int ot = 0; ot < 6; ++ot) {
        bf16x8 w = __builtin_bit_cast(bf16x8,
            *reinterpret_cast<const i32x4*>(wp0 + ot * (16 * KDIM) + kk * 32));
        acc[ot] = __builtin_amdgcn_mfma_f32_16x16x32_bf16(x0, w, acc[ot], 0, 0, 0);
      }
    }

    // ---- decode + deposit all 9 anchors (D: col=r16 -> o, row=4g+r -> px) ----
    const float ys  = (float)py * 16.0f;
    const float xs0 = (float)(q * 16) * 16.0f;
    #pragma unroll
    for (int ot = 0; ot < 6; ++ot) {
      if (sof[ot] >= 0) {
        const int ch = och[ot];
        float* sd = stg + sof[ot];
        #pragma unroll
        for (int r = 0; r < 4; ++r) {
          const int   px = g * 4 + r;
          const float tv = acc[ot][r] + bi6[ot];
          float val;
          if (ch >= 4)      val = sigf(tv);
          else if (ch == 0) val = (sigf(tv) - 0.5f) * aw6[ot] + xs0 + (float)px * 16.0f;
          else if (ch == 1) val = (sigf(tv) - 0.5f) * ah6[ot] + ys;
          else if (ch == 2) val = __expf(tv) * aw6[ot];
          else              val = __expf(tv) * ah6[ot];
          sd[px * 85] = val;
        }
      }
    }
    bar_lds();

    // ---- dense copy-out: 9 slabs x 5440 B, contiguous + 16B-aligned ----
    {
      float* outu = out + (size_t)b * (9u * HWSZ * 85u)
                        + (unsigned)((py * 64 + q * 16) * 85);
      #pragma unroll
      for (int m = 0; m < 6; ++m) {
        if (m < 5 || tid < 500) {                // 3060 quads total
          const f32x4 v = *reinterpret_cast<const f32x4*>(stg + (tid + 512 * m) * 4);
          *reinterpret_cast<f32x4*>(outu + cOff[m]) = v;
        }
      }
    }
    // ---- write-late: prefetched X -> bf16 -> other xT buffer ----
    if (i + 1 < UPB) {
      union { i32x4 qv; unsigned short us[8]; } pk;
      #pragma unroll
      for (int j = 0; j < 8; ++j) pk.us[j] = f2bf(pf[j]);
      *reinterpret_cast<i32x4*>(&xT[(i + 1) & 1][sxe]) = pk.qv;
    }
    bar_lds();
  }
}

extern "C" void kernel_launch(void* const* d_in, const int* in_sizes, int n_in,
                              void* d_out, int out_size, void* d_ws, size_t ws_size,
                              hipStream_t stream) {
  const float* xin = (const float*)d_in[0];
  const float* cw  = (const float*)d_in[1];
  const float* cb  = (const float*)d_in[2];
  float* out = (float*)d_out;
  unsigned short* wbf = (unsigned short*)d_ws;   // 768*256*2 = 393216 bytes

  prep_w<<<dim3((NOUTP * KDIM / 4) / 256), dim3(256), 0, stream>>>(cw, wbf);
  yolo_main<<<dim3(512), dim3(512), 0, stream>>>(xin, wbf, cb, out);
}

// Round 6
// 210.101 us; speedup vs baseline: 1.1753x; 1.1753x over previous
//
#include <hip/hip_runtime.h>

typedef __attribute__((ext_vector_type(8))) short bf16x8;
typedef __attribute__((ext_vector_type(4))) float f32x4;
typedef __attribute__((ext_vector_type(4))) int i32x4;
typedef __attribute__((ext_vector_type(4))) unsigned short u16x4;

#define KDIM 256
#define HWSZ 4096
#define NOUT 765
#define NOUTP 768

// Anchors in PIXEL units: w_a = ANCHORS/16 (grid units) and every use multiplies
// by STRIDE=16, so pixel units are exact. Index 9 = dummy for padded o (never stored).
__constant__ float c_AW[10] = {10.f,16.f,33.f,30.f,62.f,59.f,116.f,156.f,373.f,0.f};
__constant__ float c_AH[10] = {13.f,30.f,23.f,61.f,45.f,119.f,90.f,198.f,326.f,0.f};

__device__ __forceinline__ unsigned short f2bf(float f) {
  unsigned u = __builtin_bit_cast(unsigned, f);
  u += 0x7fffu + ((u >> 16) & 1u);   // RNE
  return (unsigned short)(u >> 16);
}

__device__ __forceinline__ float sigf(float t) {
  return 1.0f / (1.0f + __expf(-t));
}

// LDS-hazard-only barrier (validated correct in round 5: absmax 8.0 stable).
// lgkmcnt(0): my ds ops done; s_barrier; sched_barrier(0) per rule 18 (keep later
// LDS ops from hoisting above). Unlike __syncthreads() this does NOT drain vmcnt,
// so the 18-deep output store stream and staging loads stay in flight across
// barriers; the compiler's register-reuse vmcnt waits give a one-unit-deep
// pipeline automatically (T4's counted-wait effect).
__device__ __forceinline__ void bar_lds() {
  asm volatile("s_waitcnt lgkmcnt(0)" ::: "memory");
  __builtin_amdgcn_s_barrier();
  __builtin_amdgcn_sched_barrier(0);
}

// ---- kernel 1: conv_w (765x256 f32) -> padded bf16 (768x256), rows 765..767 = 0
__global__ void prep_w(const float* __restrict__ cw, unsigned short* __restrict__ wbf) {
  int e = (blockIdx.x * 256 + threadIdx.x) * 4;
  int o = e >> 8, col = e & 255;
  f32x4 v = {0.f, 0.f, 0.f, 0.f};
  if (o < NOUT) v = *reinterpret_cast<const f32x4*>(cw + o * KDIM + col);
  u16x4 u = { f2bf(v.x), f2bf(v.y), f2bf(v.z), f2bf(v.w) };
  *reinterpret_cast<u16x4*>(wbf + e) = u;
}

// ---- kernel 2: block = (batch, image row, row half) -> 32 pixels x all 765 outputs.
// Identical to round 4 (clean traffic: FETCH 41 MB steady, WRITE 196 MB, VGPR 112,
// zero spill) EXCEPT all __syncthreads() -> bar_lds(). Single-variable change:
// round 4's 8 vmcnt(0)-draining barriers serialized the store stream; these don't.
// NO min-waves launch bound (this toolchain's (512,N>=4) forces 64/32 VGPR -> spill).
__global__ __launch_bounds__(512) void yolo_main(
    const float* __restrict__ xin,
    const unsigned short* __restrict__ wbf,
    const float* __restrict__ bias,
    float* __restrict__ out)
{
  __shared__ __align__(16) char smem[3 * 2720 * 4];          // 32640 B
  unsigned short* xT   = reinterpret_cast<unsigned short*>(smem); // [32][256] bf16, swizzled (16 KB)
  float*          stg  = reinterpret_cast<float*>(smem);          // [3][32*85] f32 (32.6 KB)

  const int bid  = blockIdx.x;
  const int ph   = bid & 1;           // row half: pixels [32ph, 32ph+32)
  const int pc   = (bid >> 1) & 63;   // image row y
  const int b    = bid >> 7;          // batch
  const int tid  = threadIdx.x;
  const int lane = tid & 63;
  const int wv   = tid >> 6;

  // ---------- stage X^T into LDS (f32 -> bf16, k-bits 3..5 XOR-swizzled by px&7) ----------
  {
    const int px     = tid & 31;
    const int c0base = (tid >> 5) << 3;          // 0..120 step 8
    const float* xsrc = xin + (size_t)b * KDIM * HWSZ + pc * 64 + ph * 32 + px;
    const int sw = (px & 7) << 3;
    #pragma unroll
    for (int i = 0; i < 2; ++i) {
      const int c0 = c0base + 128 * i;
      float v[8];
      #pragma unroll
      for (int j = 0; j < 8; ++j) v[j] = xsrc[(size_t)(c0 + j) * HWSZ];
      union { i32x4 q; unsigned short us[8]; } pk;
      #pragma unroll
      for (int j = 0; j < 8; ++j) pk.us[j] = f2bf(v[j]);
      *reinterpret_cast<i32x4*>(&xT[(px << 8) + (c0 ^ sw)]) = pk.q;
    }
  }
  bar_lds();

  const int g     = lane >> 4;
  const int r16   = lane & 15;
  const int obase = wv * 96;

  f32x4 acc[6][2];
  #pragma unroll
  for (int ot = 0; ot < 6; ++ot) {
    acc[ot][0] = f32x4{0.f, 0.f, 0.f, 0.f};
    acc[ot][1] = f32x4{0.f, 0.f, 0.f, 0.f};
  }

  const unsigned short* wptr = wbf + (unsigned)(obase + r16) * KDIM + 8 * g;
  const int xb0 = (r16 << 8);          // px = r16       (pt = 0)
  const int xb1 = ((16 + r16) << 8);   // px = 16 + r16  (pt = 1)
  const int sw0 = (r16 & 7) << 3;      // (16+r16)&7 == r16&7, same swizzle

  #pragma unroll
  for (int kk = 0; kk < 8; ++kk) {
    const int ke = (kk * 32 + 8 * g) ^ sw0;
    bf16x8 x0 = __builtin_bit_cast(bf16x8, *reinterpret_cast<const i32x4*>(&xT[xb0 + ke]));
    bf16x8 x1 = __builtin_bit_cast(bf16x8, *reinterpret_cast<const i32x4*>(&xT[xb1 + ke]));
    #pragma unroll
    for (int ot = 0; ot < 6; ++ot) {
      bf16x8 w = __builtin_bit_cast(bf16x8,
          *reinterpret_cast<const i32x4*>(wptr + ot * 16 * KDIM + kk * 32));
      acc[ot][0] = __builtin_amdgcn_mfma_f32_16x16x32_bf16(x0, w, acc[ot][0], 0, 0, 0);
      acc[ot][1] = __builtin_amdgcn_mfma_f32_16x16x32_bf16(x1, w, acc[ot][1], 0, 0, 0);
    }
  }

  bar_lds();   // all xT ds_reads complete before stg overwrites smem

  // preload bias (o >= 765 lanes read dummy, never deposited)
  float bi[6];
  #pragma unroll
  for (int ot = 0; ot < 6; ++ot) {
    const int o = obase + ot * 16 + r16;
    bi[ot] = bias[o < NOUT ? o : 0];
  }
  const float ys  = (float)pc * 16.0f;
  const float xs0 = (float)(ph * 32) * 16.0f;

  // ---------- 3 iterations x 3 anchors: deposit decoded values, then dense copy-out ----------
  #pragma unroll 1
  for (int t3 = 0; t3 < 3; ++t3) {
    const int alo = 3 * t3;
    // deposit: D layout col=r16 -> o, row=4g+r -> px = pt*16+4g+r
    #pragma unroll
    for (int ot = 0; ot < 6; ++ot) {
      const int o = obase + ot * 16 + r16;
      const int a = o / 85;                       // 9 for padded o -> never matches
      if (a >= alo && a < alo + 3) {
        const int ch = o - a * 85;
        const float aw = c_AW[a], ah = c_AH[a];
        float* sdst = stg + (a - alo) * 2720 + ch;
        #pragma unroll
        for (int pt = 0; pt < 2; ++pt) {
          #pragma unroll
          for (int r = 0; r < 4; ++r) {
            const int   pxl = pt * 16 + g * 4 + r;
            const float tv  = acc[ot][pt][r] + bi[ot];
            float val;
            if (ch >= 4)      val = sigf(tv);
            else if (ch == 0) val = (sigf(tv) - 0.5f) * aw + xs0 + (float)pxl * 16.0f;
            else if (ch == 1) val = (sigf(tv) - 0.5f) * ah + ys;
            else if (ch == 2) val = __expf(tv) * aw;
            else              val = __expf(tv) * ah;
            sdst[pxl * 85] = val;
          }
        }
      }
    }
    bar_lds();
    // copy: 3 anchors x 680 dwordx4 quads, fully dense + 16B-aligned (slab = 10880B, 64B-aligned)
    #pragma unroll 1
    for (int q = tid; q < 2040; q += 512) {
      const int al = (q >= 1360) ? 2 : (q >= 680 ? 1 : 0);
      const int a  = alo + al;
      const f32x4 v = *reinterpret_cast<const f32x4*>(stg + q * 4);
      const unsigned dstdw = ((unsigned)(b * 9 + a) * HWSZ + (unsigned)(pc * 64 + ph * 32)) * 85u
                           + (unsigned)(q - al * 680) * 4u;
      *reinterpret_cast<f32x4*>(out + dstdw) = v;
    }
    bar_lds();
  }
}

extern "C" void kernel_launch(void* const* d_in, const int* in_sizes, int n_in,
                              void* d_out, int out_size, void* d_ws, size_t ws_size,
                              hipStream_t stream) {
  const float* xin = (const float*)d_in[0];
  const float* cw  = (const float*)d_in[1];
  const float* cb  = (const float*)d_in[2];
  float* out = (float*)d_out;
  unsigned short* wbf = (unsigned short*)d_ws;   // 768*256*2 = 393216 bytes

  prep_w<<<dim3((NOUTP * KDIM / 4) / 256), dim3(256), 0, stream>>>(cw, wbf);
  yolo_main<<<dim3(16 * 64 * 2), dim3(512), 0, stream>>>(xin, wbf, cb, out);
}

// Round 7
// 163.584 us; speedup vs baseline: 1.5095x; 1.2844x over previous
//
#include <hip/hip_runtime.h>

typedef __attribute__((ext_vector_type(8))) short bf16x8;
typedef __attribute__((ext_vector_type(4))) float f32x4;
typedef __attribute__((ext_vector_type(4))) int i32x4;
typedef __attribute__((ext_vector_type(4))) unsigned short u16x4;

#define KDIM 256
#define HWSZ 4096
#define NOUT 765
#define NOUTP 768
#define TBYTES ((size_t)16 * NOUTP * HWSZ * 2)   // 100,663,296 B bf16 t-buffer

// Anchors in PIXEL units: w_a = ANCHORS/16 (grid units) and every use multiplies
// by STRIDE=16, so pixel units are exact. Index 9 = dummy for padded o.
__constant__ float c_AW[10] = {10.f,16.f,33.f,30.f,62.f,59.f,116.f,156.f,373.f,0.f};
__constant__ float c_AH[10] = {13.f,30.f,23.f,61.f,45.f,119.f,90.f,198.f,326.f,0.f};

__device__ __forceinline__ unsigned short f2bf(float f) {
  unsigned u = __builtin_bit_cast(unsigned, f);
  u += 0x7fffu + ((u >> 16) & 1u);   // RNE
  return (unsigned short)(u >> 16);
}
__device__ __forceinline__ float bf2f(unsigned short h) {
  return __builtin_bit_cast(float, ((unsigned)h) << 16);
}
__device__ __forceinline__ float sigf(float t) {
  return 1.0f / (1.0f + __expf(-t));
}

// LDS-hazard-only barrier (validated rounds 5/6: correct, absmax stable).
__device__ __forceinline__ void bar_lds() {
  asm volatile("s_waitcnt lgkmcnt(0)" ::: "memory");
  __builtin_amdgcn_s_barrier();
  __builtin_amdgcn_sched_barrier(0);
}

// ---- prep: conv_w (765x256 f32) -> padded bf16 (768x256), rows 765..767 = 0
__global__ void prep_w(const float* __restrict__ cw, unsigned short* __restrict__ wbf) {
  int e = (blockIdx.x * 256 + threadIdx.x) * 4;
  int o = e >> 8, col = e & 255;
  f32x4 v = {0.f, 0.f, 0.f, 0.f};
  if (o < NOUT) v = *reinterpret_cast<const f32x4*>(cw + o * KDIM + col);
  u16x4 u = { f2bf(v.x), f2bf(v.y), f2bf(v.z), f2bf(v.w) };
  *reinterpret_cast<u16x4*>(wbf + e) = u;
}

// ================= SPLIT PATH =================
// K1: pure GEMM. block = (b, image row) = 64 px x all 768 outputs (r1 structure).
// Epilogue: bias + bf16 pack + direct store to t[b][o][4096]. Each o-row receives
// exactly one full 128B line per block (px 0..63 as bf16), 128B-aligned: dense,
// line-complete, no staging, no transcendentals, ONE barrier per block.
__global__ __launch_bounds__(512) void k1_gemm(
    const float* __restrict__ xin,
    const unsigned short* __restrict__ wbf,
    const float* __restrict__ bias,
    unsigned short* __restrict__ t)
{
  __shared__ __align__(16) unsigned short xT[64 * KDIM];  // 32 KB, k-bits 3..5 XOR-swizzled by px&7

  const int b    = blockIdx.x >> 6;
  const int pc   = blockIdx.x & 63;
  const int tid  = threadIdx.x;
  const int lane = tid & 63;
  const int wv   = tid >> 6;

  // stage X^T (f32 -> bf16, swizzled); lanes = px -> 256B coalesced per c-row
  {
    const float* xsrc = xin + ((size_t)b * KDIM) * HWSZ + pc * 64;
    const int p  = lane;
    const int sw = (p & 7) << 3;
    #pragma unroll
    for (int i = 0; i < 4; ++i) {
      const int c0 = (wv + 8 * i) << 3;
      float v[8];
      #pragma unroll
      for (int j = 0; j < 8; ++j) v[j] = xsrc[(size_t)(c0 + j) * HWSZ + p];
      union { i32x4 q; unsigned short us[8]; } pk;
      #pragma unroll
      for (int j = 0; j < 8; ++j) pk.us[j] = f2bf(v[j]);
      *reinterpret_cast<i32x4*>(&xT[(p << 8) + (c0 ^ sw)]) = pk.q;
    }
  }
  bar_lds();

  const int g     = lane >> 4;
  const int r16   = lane & 15;
  const int obase = wv * 96;

  f32x4 acc[6][4];
  #pragma unroll
  for (int ot = 0; ot < 6; ++ot)
    #pragma unroll
    for (int pt = 0; pt < 4; ++pt)
      acc[ot][pt] = f32x4{0.f, 0.f, 0.f, 0.f};

  const unsigned short* wptr = wbf + (unsigned)(obase + r16) * KDIM + 8 * g;
  const int sw0 = (r16 & 7) << 3;     // (pt*16+r16)&7 == r16&7 for all pt

  #pragma unroll
  for (int kk = 0; kk < 8; ++kk) {
    const int ke = (kk * 32 + 8 * g) ^ sw0;
    bf16x8 xfr[4];
    #pragma unroll
    for (int pt = 0; pt < 4; ++pt)
      xfr[pt] = __builtin_bit_cast(bf16x8,
          *reinterpret_cast<const i32x4*>(&xT[((pt * 16 + r16) << 8) + ke]));
    #pragma unroll
    for (int ot = 0; ot < 6; ++ot) {
      bf16x8 w = __builtin_bit_cast(bf16x8,
          *reinterpret_cast<const i32x4*>(wptr + ot * 16 * KDIM + kk * 32));
      #pragma unroll
      for (int pt = 0; pt < 4; ++pt)
        acc[ot][pt] = __builtin_amdgcn_mfma_f32_16x16x32_bf16(xfr[pt], w, acc[ot][pt], 0, 0, 0);
    }
  }

  // epilogue: D col=r16 -> o, row=4g+r -> px = pt*16+4g+r. Pack 4 px (r=0..3) as
  // bf16x4 -> 8B store; pt x g tile one full 128B line per o-row.
  #pragma unroll
  for (int ot = 0; ot < 6; ++ot) {
    const int o  = obase + ot * 16 + r16;
    const float bi = bias[o < NOUT ? o : 0];
    unsigned short* trow = t + (size_t)(b * NOUTP + o) * HWSZ + pc * 64;
    #pragma unroll
    for (int pt = 0; pt < 4; ++pt) {
      u16x4 pk = { f2bf(acc[ot][pt].x + bi), f2bf(acc[ot][pt].y + bi),
                   f2bf(acc[ot][pt].z + bi), f2bf(acc[ot][pt].w + bi) };
      *reinterpret_cast<u16x4*>(trow + pt * 16 + 4 * g) = pk;
    }
  }
}

// K2: decode + transpose, pure streaming. block = (b, a, 128-px chunk).
// Stage: read t[85ch][128px] bf16 coalesced, decode (ch = e4>>5: shifts only),
// write f32 to lds[px][ch]. Copy-out: linear ds_read_b128 + dense dwordx4 records.
__global__ __launch_bounds__(256) void k2_decode(
    const unsigned short* __restrict__ t,
    float* __restrict__ out)
{
  __shared__ __align__(16) float lds[128 * 85];   // 43520 B

  const int tid   = threadIdx.x;
  const int chunk = blockIdx.x & 31;              // 128-px chunk of 4096
  const int ba    = blockIdx.x >> 5;              // b*9 + a
  const int a     = ba % 9;
  const int hw0   = chunk << 7;
  const float aw  = c_AW[a], ah = c_AH[a];

  const unsigned short* tb = t + (size_t)((ba / 9) * NOUTP + a * 85) * HWSZ + hw0;

  #pragma unroll 1
  for (int e4 = tid; e4 < 2720; e4 += 256) {      // 85 ch-rows x 32 px-quads
    const int ch  = e4 >> 5;
    const int px0 = (e4 & 31) << 2;
    const u16x4 raw = *reinterpret_cast<const u16x4*>(tb + (size_t)ch * HWSZ + px0);
    #pragma unroll
    for (int j = 0; j < 4; ++j) {
      const float v  = bf2f(raw[j]);
      const int   hw = hw0 + px0 + j;
      float val;
      if (ch >= 4)      val = sigf(v);
      else if (ch == 0) val = (sigf(v) - 0.5f) * aw + (float)(hw & 63) * 16.0f;
      else if (ch == 1) val = (sigf(v) - 0.5f) * ah + (float)(hw >> 6) * 16.0f;
      else if (ch == 2) val = __expf(v) * aw;
      else              val = __expf(v) * ah;
      lds[(px0 + j) * 85 + ch] = val;
    }
  }
  __syncthreads();

  float* ob = out + ((size_t)ba * HWSZ + hw0) * 85;
  #pragma unroll 1
  for (int q = tid; q < 2720; q += 256)
    *reinterpret_cast<f32x4*>(ob + q * 4) = *reinterpret_cast<const f32x4*>(lds + q * 4);
}

// ================= FALLBACK (round-6 fused kernel, passing at 210us) =================
__global__ __launch_bounds__(512) void yolo_fused(
    const float* __restrict__ xin,
    const unsigned short* __restrict__ wbf,
    const float* __restrict__ bias,
    float* __restrict__ out)
{
  __shared__ __align__(16) char smem[3 * 2720 * 4];
  unsigned short* xT  = reinterpret_cast<unsigned short*>(smem);
  float*          stg = reinterpret_cast<float*>(smem);

  const int bid  = blockIdx.x;
  const int ph   = bid & 1;
  const int pc   = (bid >> 1) & 63;
  const int b    = bid >> 7;
  const int tid  = threadIdx.x;
  const int lane = tid & 63;
  const int wv   = tid >> 6;

  {
    const int px     = tid & 31;
    const int c0base = (tid >> 5) << 3;
    const float* xsrc = xin + (size_t)b * KDIM * HWSZ + pc * 64 + ph * 32 + px;
    const int sw = (px & 7) << 3;
    #pragma unroll
    for (int i = 0; i < 2; ++i) {
      const int c0 = c0base + 128 * i;
      float v[8];
      #pragma unroll
      for (int j = 0; j < 8; ++j) v[j] = xsrc[(size_t)(c0 + j) * HWSZ];
      union { i32x4 q; unsigned short us[8]; } pk;
      #pragma unroll
      for (int j = 0; j < 8; ++j) pk.us[j] = f2bf(v[j]);
      *reinterpret_cast<i32x4*>(&xT[(px << 8) + (c0 ^ sw)]) = pk.q;
    }
  }
  bar_lds();

  const int g = lane >> 4, r16 = lane & 15, obase = wv * 96;
  f32x4 acc[6][2];
  #pragma unroll
  for (int ot = 0; ot < 6; ++ot) { acc[ot][0] = f32x4{0,0,0,0}; acc[ot][1] = f32x4{0,0,0,0}; }

  const unsigned short* wptr = wbf + (unsigned)(obase + r16) * KDIM + 8 * g;
  const int xb0 = (r16 << 8), xb1 = ((16 + r16) << 8), sw0 = (r16 & 7) << 3;

  #pragma unroll
  for (int kk = 0; kk < 8; ++kk) {
    const int ke = (kk * 32 + 8 * g) ^ sw0;
    bf16x8 x0 = __builtin_bit_cast(bf16x8, *reinterpret_cast<const i32x4*>(&xT[xb0 + ke]));
    bf16x8 x1 = __builtin_bit_cast(bf16x8, *reinterpret_cast<const i32x4*>(&xT[xb1 + ke]));
    #pragma unroll
    for (int ot = 0; ot < 6; ++ot) {
      bf16x8 w = __builtin_bit_cast(bf16x8,
          *reinterpret_cast<const i32x4*>(wptr + ot * 16 * KDIM + kk * 32));
      acc[ot][0] = __builtin_amdgcn_mfma_f32_16x16x32_bf16(x0, w, acc[ot][0], 0, 0, 0);
      acc[ot][1] = __builtin_amdgcn_mfma_f32_16x16x32_bf16(x1, w, acc[ot][1], 0, 0, 0);
    }
  }
  bar_lds();

  float bi[6];
  #pragma unroll
  for (int ot = 0; ot < 6; ++ot) {
    const int o = obase + ot * 16 + r16;
    bi[ot] = bias[o < NOUT ? o : 0];
  }
  const float ys = (float)pc * 16.0f, xs0 = (float)(ph * 32) * 16.0f;

  #pragma unroll 1
  for (int t3 = 0; t3 < 3; ++t3) {
    const int alo = 3 * t3;
    #pragma unroll
    for (int ot = 0; ot < 6; ++ot) {
      const int o = obase + ot * 16 + r16;
      const int a = o / 85;
      if (a >= alo && a < alo + 3) {
        const int ch = o - a * 85;
        const float aw = c_AW[a], ah = c_AH[a];
        float* sdst = stg + (a - alo) * 2720 + ch;
        #pragma unroll
        for (int pt = 0; pt < 2; ++pt) {
          #pragma unroll
          for (int r = 0; r < 4; ++r) {
            const int   pxl = pt * 16 + g * 4 + r;
            const float tv  = acc[ot][pt][r] + bi[ot];
            float val;
            if (ch >= 4)      val = sigf(tv);
            else if (ch == 0) val = (sigf(tv) - 0.5f) * aw + xs0 + (float)pxl * 16.0f;
            else if (ch == 1) val = (sigf(tv) - 0.5f) * ah + ys;
            else if (ch == 2) val = __expf(tv) * aw;
            else              val = __expf(tv) * ah;
            sdst[pxl * 85] = val;
          }
        }
      }
    }
    bar_lds();
    #pragma unroll 1
    for (int q = tid; q < 2040; q += 512) {
      const int al = (q >= 1360) ? 2 : (q >= 680 ? 1 : 0);
      const int a  = alo + al;
      const f32x4 v = *reinterpret_cast<const f32x4*>(stg + q * 4);
      const unsigned dstdw = ((unsigned)(b * 9 + a) * HWSZ + (unsigned)(pc * 64 + ph * 32)) * 85u
                           + (unsigned)(q - al * 680) * 4u;
      *reinterpret_cast<f32x4*>(out + dstdw) = v;
    }
    bar_lds();
  }
}

extern "C" void kernel_launch(void* const* d_in, const int* in_sizes, int n_in,
                              void* d_out, int out_size, void* d_ws, size_t ws_size,
                              hipStream_t stream) {
  const float* xin = (const float*)d_in[0];
  const float* cw  = (const float*)d_in[1];
  const float* cb  = (const float*)d_in[2];
  float* out = (float*)d_out;

  if (ws_size >= TBYTES + 393216) {
    unsigned short* t   = (unsigned short*)d_ws;
    unsigned short* wbf = (unsigned short*)((char*)d_ws + TBYTES);
    prep_w<<<dim3((NOUTP * KDIM / 4) / 256), dim3(256), 0, stream>>>(cw, wbf);
    k1_gemm<<<dim3(16 * 64), dim3(512), 0, stream>>>(xin, wbf, cb, t);
    k2_decode<<<dim3(16 * 9 * 32), dim3(256), 0, stream>>>(t, out);
  } else {
    unsigned short* wbf = (unsigned short*)d_ws;   // 393216 B
    prep_w<<<dim3((NOUTP * KDIM / 4) / 256), dim3(256), 0, stream>>>(cw, wbf);
    yolo_fused<<<dim3(16 * 64 * 2), dim3(512), 0, stream>>>(xin, wbf, cb, out);
  }
}